// Round 7
// baseline (2275.311 us; speedup 1.0000x reference)
//
#include <hip/hip_runtime.h>
#include <math.h>

#define NCHUNK 32
typedef unsigned long long ull;

__device__ __forceinline__ float gelu_f(float v){
  return 0.5f*v*(1.0f+erff(v*0.70710678118654752440f));
}

__device__ __forceinline__ unsigned flipf(float d){
  unsigned u = __float_as_uint(d);
  return (u & 0x80000000u) ? ~u : (u | 0x80000000u);
}

// ---- DPP wave reductions on u64 keys; readlane finish (no LDS ops) ----
// XOR1=quad_perm(0xB1), XOR2=quad_perm(0x4E), XOR7=row_half_mirror(0x141),
// XOR15=row_mirror(0x140). After these, each 16-lane group is uniform;
// finish with readlane of lanes 0,16,32,48 -> wave-uniform result.
template<int CTRL>
__device__ __forceinline__ ull kmax_dpp(ull k){
  int lo = __builtin_amdgcn_update_dpp(0, (int)(unsigned)k,       CTRL, 0xF, 0xF, true);
  int hi = __builtin_amdgcn_update_dpp(0, (int)(unsigned)(k>>32), CTRL, 0xF, 0xF, true);
  ull o = ((ull)(unsigned)hi<<32) | (unsigned)lo;
  return o > k ? o : k;
}
template<int CTRL>
__device__ __forceinline__ ull kmin_dpp(ull k){
  int lo = __builtin_amdgcn_update_dpp(0, (int)(unsigned)k,       CTRL, 0xF, 0xF, true);
  int hi = __builtin_amdgcn_update_dpp(0, (int)(unsigned)(k>>32), CTRL, 0xF, 0xF, true);
  ull o = ((ull)(unsigned)hi<<32) | (unsigned)lo;
  return o < k ? o : k;
}
__device__ __forceinline__ ull rl64(ull k, int l){
  unsigned lo = (unsigned)__builtin_amdgcn_readlane((int)(unsigned)k, l);
  unsigned hi = (unsigned)__builtin_amdgcn_readlane((int)(unsigned)(k>>32), l);
  return ((ull)hi<<32) | lo;
}
__device__ __forceinline__ ull wave_kmax(ull k){
  k = kmax_dpp<0xB1>(k);
  k = kmax_dpp<0x4E>(k);
  k = kmax_dpp<0x141>(k);
  k = kmax_dpp<0x140>(k);
  ull a = rl64(k,0), b = rl64(k,16), c = rl64(k,32), d = rl64(k,48);
  ull ab = a > b ? a : b, cd = c > d ? c : d;
  return ab > cd ? ab : cd;
}
__device__ __forceinline__ ull wave_kmin(ull k){
  k = kmin_dpp<0xB1>(k);
  k = kmin_dpp<0x4E>(k);
  k = kmin_dpp<0x141>(k);
  k = kmin_dpp<0x140>(k);
  ull a = rl64(k,0), b = rl64(k,16), c = rl64(k,32), d = rl64(k,48);
  ull ab = a < b ? a : b, cd = c < d ? c : d;
  return ab < cd ? ab : cd;
}

// ============ wave-per-query kNN in 3D (optional fused cur-mean, K==8) ============
// key = (flip(d)<<32) | idx ; lex order == (d asc, idx asc) == stable top_k order.
template<int K>
__global__ __launch_bounds__(256) void knn_wave(
    const float* __restrict__ cand, int n,
    const float* __restrict__ qsrc, const int* __restrict__ qidx, int m,
    int* __restrict__ nbr, float* __restrict__ outc)
{
  __shared__ float cx[1024], cy[1024], cz[1024], cbb[1024];
  int b = blockIdx.y;
  int wv = threadIdx.x >> 6, lane = threadIdx.x & 63;
  int q = blockIdx.x*4 + wv;           // m is always a multiple of 4
  const float* cb = cand + (size_t)b*3*n;
  int qi = qidx ? qidx[(size_t)b*m + q] : q;
  const float* qb = qsrc + (size_t)b*3*n;
  float qx = qb[qi], qy = qb[n+qi], qz = qb[2*n+qi];
  float aa = (qx*qx + qy*qy) + qz*qz;

  ull a[K];
  #pragma unroll
  for (int k=0;k<K;k++) a[k] = ~0ull;
  ull worst = ~0ull; int wslot = 0;

  for (int base=0; base<n; base+=1024){
    int cnt = min(1024, n-base);
    for (int j=threadIdx.x; j<cnt; j+=256){
      float x=cb[base+j], y=cb[n+base+j], z=cb[2*n+base+j];
      cx[j]=x; cy[j]=y; cz[j]=z; cbb[j]=(x*x+y*y)+z*z;
    }
    __syncthreads();
    int steps = cnt >> 6;
    for (int i=0;i<steps;i++){
      int j = lane + (i<<6);
      float d = aa + cbb[j] - 2.0f*((qx*cx[j]+qy*cy[j])+qz*cz[j]);
      ull key = ((ull)flipf(d)<<32) | (unsigned)(base+j);
      if (key < worst){
        #pragma unroll
        for (int k=0;k<K;k++) if (k==wslot) a[k] = key;
        worst = a[0]; wslot = 0;
        #pragma unroll
        for (int k=1;k<K;k++){
          bool g = a[k] > worst;
          worst = g ? a[k] : worst;
          wslot = g ? k : wslot;
        }
      }
    }
    __syncthreads();
  }

  // per-lane bitonic sort ascending
  #pragma unroll
  for (int kk=2; kk<=K; kk<<=1)
    #pragma unroll
    for (int jj=kk>>1; jj>0; jj>>=1)
      #pragma unroll
      for (int i=0;i<K;i++){
        int l = i ^ jj;
        if (l > i){
          bool dirUp = ((i & kk) == 0);
          ull x = a[i], y = a[l];
          bool sw = dirUp ? (x > y) : (x < y);
          a[i] = sw ? y : x;
          a[l] = sw ? x : y;
        }
      }

  // K rounds of wave-min extraction (DPP+readlane) with sorted-list pop
  ull head = a[0];
  int res[K];
  #pragma unroll
  for (int r=0; r<K; r++){
    ull mk = wave_kmin(head);        // uniform
    res[r] = (int)(unsigned)mk;
    if (head == mk){
      #pragma unroll
      for (int i2=0;i2<K-1;i2++) a[i2]=a[i2+1];
      a[K-1] = ~0ull;
      head = a[0];
    }
  }
  if (lane == 0){
    int* o = nbr + ((size_t)b*m + q)*K;
    #pragma unroll
    for (int r=0;r<K;r++) o[r] = res[r];
  }
  // fused xyz-downsample mean (only used for K==8 sampled-kNN)
  if (outc != nullptr && lane < 3){
    const float* cd = cb + (size_t)lane*n;
    float s=0;
    #pragma unroll
    for (int k=0;k<K;k++) s += cd[res[k]];
    outc[((size_t)b*3 + lane)*m + q] = s * (1.0f/K);
  }
}

// ============ wave-per-query top-K from Gram rows (coalesced) ============
template<int K>
__global__ __launch_bounds__(256) void topk_wave(
    const float* __restrict__ G, const float* __restrict__ aa, int m,
    int* __restrict__ nbr)
{
  __shared__ float abs_s[1024];
  int b = blockIdx.y;
  int wv = threadIdx.x >> 6, lane = threadIdx.x & 63;
  int q = blockIdx.x*4 + wv;
  const float* ab = aa + (size_t)b*m;
  for (int j=threadIdx.x; j<m; j+=256) abs_s[j] = ab[j];
  __syncthreads();
  float aq = ab[q];
  const float* Gq = G + ((size_t)b*m + q)*m;   // row; bitwise symmetric Gram

  ull a[K];
  #pragma unroll
  for (int k=0;k<K;k++) a[k] = ~0ull;
  ull worst = ~0ull; int wslot = 0;

  int steps = (m+63)>>6;
  for (int i=0;i<steps;i++){
    int j = lane + (i<<6);
    ull key = ~0ull;
    if (j < m){
      float g = Gq[j];
      float d = aq + abs_s[j] - 2.0f*g;
      key = ((ull)flipf(d)<<32) | (unsigned)j;
    }
    if (key < worst){
      #pragma unroll
      for (int k=0;k<K;k++) if (k==wslot) a[k] = key;
      worst = a[0]; wslot = 0;
      #pragma unroll
      for (int k=1;k<K;k++){
        bool g = a[k] > worst;
        worst = g ? a[k] : worst;
        wslot = g ? k : wslot;
      }
    }
  }

  #pragma unroll
  for (int kk=2; kk<=K; kk<<=1)
    #pragma unroll
    for (int jj=kk>>1; jj>0; jj>>=1)
      #pragma unroll
      for (int i=0;i<K;i++){
        int l = i ^ jj;
        if (l > i){
          bool dirUp = ((i & kk) == 0);
          ull x = a[i], y = a[l];
          bool sw = dirUp ? (x > y) : (x < y);
          a[i] = sw ? y : x;
          a[l] = sw ? x : y;
        }
      }

  ull head = a[0];
  int res[K];
  #pragma unroll
  for (int r=0; r<K; r++){
    ull mk = wave_kmin(head);
    res[r] = (int)(unsigned)mk;
    if (head == mk){
      #pragma unroll
      for (int i2=0;i2<K-1;i2++) a[i2]=a[i2+1];
      a[K-1] = ~0ull;
      head = a[0];
    }
  }
  if (lane == 0){
    int* o = nbr + ((size_t)b*m + q)*K;
    #pragma unroll
    for (int r=0;r<K;r++) o[r] = res[r];
  }
}

// ============ multi-wave FPS (stage 0) with DPP+readlane argmax ============
template<int NP, int T, int M>
__global__ __launch_bounds__(T,1) void fps_mw(const float* __restrict__ cur, int n,
                                              int* __restrict__ sind)
{
  constexpr int NW = T/64;
  int b = blockIdx.x, tid = threadIdx.x;
  int wv = tid>>6;
  const float* cb = cur + (size_t)b*3*n;
  __shared__ float4 lp[NP*T];
  __shared__ ull wred[2][NW];
  float px[NP], py[NP], pz[NP], dmin[NP];
  unsigned nj[NP];
  #pragma unroll
  for (int s=0;s<NP;s++){
    int j = tid + s*T;
    px[s]=cb[j]; py[s]=cb[n+j]; pz[s]=cb[2*n+j]; dmin[s]=1e30f;
    nj[s] = (unsigned)(~j);
    lp[j] = make_float4(px[s],py[s],pz[s],0.f);
  }
  __syncthreads();
  float X = lp[0].x, Y = lp[0].y, Z = lp[0].z;
  if (tid==0) sind[(size_t)b*M] = 0;
  int p = 0;
  for (int step=1; step<M; step++){
    ull key[NP];
    #pragma unroll
    for (int s=0;s<NP;s++){
      float dx=px[s]-X, dy=py[s]-Y, dz=pz[s]-Z;
      float d = (dx*dx + dy*dy) + dz*dz;
      float nd = fminf(dmin[s], d);
      dmin[s] = nd;
      key[s] = ((ull)__float_as_uint(nd)<<32) | nj[s];
    }
    #pragma unroll
    for (int w=NP; w>1; w>>=1)
      #pragma unroll
      for (int i=0;i<NP;i++) if (i < (w>>1))
        key[i] = key[i] >= key[i+(w>>1)] ? key[i] : key[i+(w>>1)];
    ull wk = wave_kmax(key[0]);      // uniform per wave
    if ((tid&63)==0) wred[p][wv] = wk;
    __syncthreads();
    ull gk = wred[p][0];
    #pragma unroll
    for (int w=1;w<NW;w++){
      ull o = wred[p][w];
      gk = gk >= o ? gk : o;
    }
    int gi = (int)(~(unsigned)gk);
    if (tid==0) sind[(size_t)b*M + step] = gi;
    float4 wp = lp[gi];
    X=wp.x; Y=wp.y; Z=wp.z;
    p ^= 1;
  }
}

// ============ single-wave FPS (stages 1-3): no barriers, no cross-wave merge ============
template<int NP, int M>
__global__ __launch_bounds__(64,1) void fps_sw(const float* __restrict__ cur, int n,
                                               int* __restrict__ sind)
{
  int b = blockIdx.x, lane = threadIdx.x;
  const float* cb = cur + (size_t)b*3*n;
  __shared__ float4 lp[NP*64];
  float px[NP], py[NP], pz[NP], dmin[NP];
  unsigned nj[NP];
  #pragma unroll
  for (int s=0;s<NP;s++){
    int j = lane + s*64;
    px[s]=cb[j]; py[s]=cb[n+j]; pz[s]=cb[2*n+j]; dmin[s]=1e30f;
    nj[s] = (unsigned)(~j);
    lp[j] = make_float4(px[s],py[s],pz[s],0.f);
  }
  __syncthreads();
  float X = lp[0].x, Y = lp[0].y, Z = lp[0].z;
  if (lane==0) sind[(size_t)b*M] = 0;
  for (int step=1; step<M; step++){
    ull key[NP];
    #pragma unroll
    for (int s=0;s<NP;s++){
      float dx=px[s]-X, dy=py[s]-Y, dz=pz[s]-Z;
      float d = (dx*dx + dy*dy) + dz*dz;
      float nd = fminf(dmin[s], d);
      dmin[s] = nd;
      key[s] = ((ull)__float_as_uint(nd)<<32) | nj[s];
    }
    #pragma unroll
    for (int w=NP; w>1; w>>=1)
      #pragma unroll
      for (int i=0;i<NP;i++) if (i < (w>>1))
        key[i] = key[i] >= key[i+(w>>1)] ? key[i] : key[i+(w>>1)];
    ull gk = wave_kmax(key[0]);
    int gi = (int)(~(unsigned)gk);
    if (lane==0) sind[(size_t)b*M + step] = gi;
    float4 wp = lp[gi];
    X=wp.x; Y=wp.y; Z=wp.z;
  }
}

// ---------------- tiled NT GEMM (optional fused BN+gelu on A-load) ----------------
template<bool DUAL, bool BN>
__global__ __launch_bounds__(256) void gemm_nt(
    const float* __restrict__ A, const float* __restrict__ B,
    float* __restrict__ out0, float* __restrict__ out1,
    int M, int N, int Kd, int lda, int ldb, int ldo, int boff,
    long sA, long sB, long sO, const float* __restrict__ bnst)
{
  int bz = blockIdx.z;
  A += (size_t)bz * sA; B += (size_t)bz * sB;
  float* o0 = out0 + (size_t)bz * sO;
  float* o1 = DUAL ? (out1 + (size_t)bz * sO) : nullptr;
  int rowBase = blockIdx.y*64, colBase = blockIdx.x*64;
  __shared__ float As[16][64], Bs0[16][64];
  __shared__ float Bs1[DUAL?16:1][64];
  int tid = threadIdx.x;
  int ty = tid>>4, tx = tid&15;
  float acc0[4][4] = {}, acc1[4][4] = {};
  int lr = tid>>2, lk = (tid&3)*4;
  for (int k0=0; k0<Kd; k0+=16) {
    float4 va = make_float4(0,0,0,0);
    int r = rowBase + lr;
    if (r < M) va = *(const float4*)(A + (size_t)r*lda + k0 + lk);
    if (BN){
      int c = k0 + lk;
      va.x = gelu_f((va.x - bnst[c+0]) / sqrtf(bnst[512+c+0] + 1e-5f));
      va.y = gelu_f((va.y - bnst[c+1]) / sqrtf(bnst[512+c+1] + 1e-5f));
      va.z = gelu_f((va.z - bnst[c+2]) / sqrtf(bnst[512+c+2] + 1e-5f));
      va.w = gelu_f((va.w - bnst[c+3]) / sqrtf(bnst[512+c+3] + 1e-5f));
    }
    As[lk+0][lr]=va.x; As[lk+1][lr]=va.y; As[lk+2][lr]=va.z; As[lk+3][lr]=va.w;
    float4 vb = make_float4(0,0,0,0), vb2 = make_float4(0,0,0,0);
    int c2 = colBase + lr;
    if (c2 < N) {
      vb = *(const float4*)(B + (size_t)c2*ldb + k0 + lk);
      if (DUAL) vb2 = *(const float4*)(B + (size_t)c2*ldb + boff + k0 + lk);
    }
    Bs0[lk+0][lr]=vb.x; Bs0[lk+1][lr]=vb.y; Bs0[lk+2][lr]=vb.z; Bs0[lk+3][lr]=vb.w;
    if (DUAL) {
      Bs1[lk+0][lr]=vb2.x-vb.x; Bs1[lk+1][lr]=vb2.y-vb.y;
      Bs1[lk+2][lr]=vb2.z-vb.z; Bs1[lk+3][lr]=vb2.w-vb.w;
    }
    __syncthreads();
    #pragma unroll
    for (int kk=0;kk<16;kk++){
      float4 a  = *(const float4*)&As[kk][ty*4];
      float4 b0 = *(const float4*)&Bs0[kk][tx*4];
      float av[4]={a.x,a.y,a.z,a.w};
      float b0v[4]={b0.x,b0.y,b0.z,b0.w};
      #pragma unroll
      for (int i=0;i<4;i++)
        #pragma unroll
        for (int j=0;j<4;j++) acc0[i][j] = fmaf(av[i], b0v[j], acc0[i][j]);
      if (DUAL) {
        float4 b1 = *(const float4*)&Bs1[kk][tx*4];
        float b1v[4]={b1.x,b1.y,b1.z,b1.w};
        #pragma unroll
        for (int i=0;i<4;i++)
          #pragma unroll
          for (int j=0;j<4;j++) acc1[i][j] = fmaf(av[i], b1v[j], acc1[i][j]);
      }
    }
    __syncthreads();
  }
  #pragma unroll
  for (int i=0;i<4;i++){
    int r = rowBase + ty*4 + i;
    if (r < M) {
      #pragma unroll
      for (int j=0;j<4;j++){
        int c = colBase + tx*4 + j;
        if (c < N) {
          o0[(size_t)r*ldo + c] = acc0[i][j];
          if (DUAL) o1[(size_t)r*ldo + c] = acc1[i][j];
        }
      }
    }
  }
}

// ---------------- gather + max over K neighbors (+ optional adds) ----------------
__global__ __launch_bounds__(256) void gathermax_kernel(
    const float* __restrict__ P, const int* __restrict__ nbr,
    const float* __restrict__ addA, const float* __restrict__ addB,
    float* __restrict__ out, int n_out, int n_src, int O, int K, int total)
{
  int e = blockIdx.x*256 + threadIdx.x;
  if (e >= total) return;
  int o = e % O; int r = e / O;
  int b = r / n_out; int i = r % n_out;
  const int* nb = nbr + ((size_t)b*n_out + i)*K;
  float mx = -1e38f;
  for (int k=0;k<K;k++){
    int j = nb[k];
    float v = P[((size_t)b*n_src + j)*O + o];
    mx = fmaxf(mx, v);
  }
  float res = mx;
  if (addA) res += addA[e];
  if (addB) res = addB[e] + res;
  out[e] = res;
}

// ---------------- deterministic per-channel stats (partials) ----------------
__global__ void stats_part_kernel(const float* __restrict__ x, int R, int O,
                                  float* __restrict__ part)
{
  int o = threadIdx.x;
  int chunk = blockIdx.x;
  int per = (R + NCHUNK - 1)/NCHUNK;
  int r0 = chunk*per, r1 = min(r0+per, R);
  float s=0, q=0;
  for (int r=r0; r<r1; r++){ float v = x[(size_t)r*O + o]; s+=v; q+=v*v; }
  part[(size_t)chunk*1024 + o] = s;
  part[(size_t)(NCHUNK+chunk)*1024 + o] = q;
}

// finalize mu/var (fixed order, bit-identical to bngelu's finalize)
__global__ void stats_fin(const float* __restrict__ part, float* __restrict__ st,
                          float invR)
{
  int o = threadIdx.x;
  float s=0, q=0;
  #pragma unroll 4
  for (int c=0;c<NCHUNK;c++){
    s += part[(size_t)c*1024 + o];
    q += part[(size_t)(NCHUNK+c)*1024 + o];
  }
  float mu = s*invR;
  st[o] = mu;
  st[512+o] = q*invR - mu*mu;
}

// fused finalize + BN + gelu (in-place)
__global__ __launch_bounds__(256) void bngelu_kernel(float* __restrict__ x,
    const float* __restrict__ part, float invR, int O, int total)
{
  __shared__ float mu_s[512], var_s[512];
  for (int oo=threadIdx.x; oo<O; oo+=256){
    float s=0, q=0;
    #pragma unroll 4
    for (int c=0;c<NCHUNK;c++){
      s += part[(size_t)c*1024 + oo];
      q += part[(size_t)(NCHUNK+c)*1024 + oo];
    }
    float mu = s*invR;
    mu_s[oo] = mu;
    var_s[oo] = q*invR - mu*mu;
  }
  __syncthreads();
  int e = blockIdx.x*256 + threadIdx.x;
  if (e >= total) return;
  int o = e % O;
  float v = (x[e]-mu_s[o]) / sqrtf(var_s[o] + 1e-5f);
  x[e] = gelu_f(v);
}

// ---------------- initial 3->64 MLP ----------------
__global__ __launch_bounds__(256) void mlp_kernel(const float* __restrict__ x,
    const float* __restrict__ w, const float* __restrict__ bias,
    float* __restrict__ out, int N, int total)
{
  int e = blockIdx.x*256 + threadIdx.x;
  if (e >= total) return;
  int o = e & 63; int r = e >> 6;
  int b = r / N; int i = r % N;
  const float* xb = x + (size_t)b*3*N;
  float v = ((w[o*3+0]*xb[i] + w[o*3+1]*xb[N+i]) + w[o*3+2]*xb[2*N+i]) + bias[o];
  out[e] = v;
}

// ---------------- per-point squared norms ----------------
__global__ __launch_bounds__(256) void norms_kernel(const float* __restrict__ h,
    float* __restrict__ aa, int C, int total)
{
  int e = blockIdx.x*256 + threadIdx.x;
  if (e >= total) return;
  const float* r = h + (size_t)e*C;
  float s=0;
  for (int c=0;c<C;c++) s += r[c]*r[c];
  aa[e]=s;
}

// ---------------- head ----------------
__global__ __launch_bounds__(1024) void head_kernel(const float* __restrict__ h,
    const float* __restrict__ w1, const float* __restrict__ w2,
    const float* __restrict__ b2, float* __restrict__ out)
{
  __shared__ __align__(16) float g[4*512];
  __shared__ __align__(16) float t[4*256];
  int tid = threadIdx.x;
  for (int e=tid; e<2048; e+=1024){
    int b=e>>9, c=e&511;
    float s=0;
    for (int p=0;p<16;p++) s += h[((size_t)(b*16+p))*512 + c];
    g[e] = s * (1.0f/16.0f);
  }
  __syncthreads();
  {
    int b = tid>>8, j = tid&255;
    const float4* gr = (const float4*)(g + b*512);
    const float4* wr = (const float4*)(w1 + (size_t)j*512);
    float s=0;
    for (int c=0;c<128;c++){
      float4 a=gr[c], w=wr[c];
      s = fmaf(a.x,w.x, fmaf(a.y,w.y, fmaf(a.z,w.z, fmaf(a.w,w.w, s))));
    }
    t[tid] = s;
  }
  __syncthreads();
  if (tid < 256){
    float v0=t[tid], v1=t[256+tid], v2=t[512+tid], v3=t[768+tid];
    float mu = ((v0+v1)+v2+v3)*0.25f;
    float d0=v0-mu, d1=v1-mu, d2=v2-mu, d3=v3-mu;
    float var = ((d0*d0+d1*d1)+d2*d2+d3*d3)*0.25f;
    float sq = sqrtf(var + 1e-5f);
    t[tid]     = gelu_f(d0/sq);
    t[256+tid] = gelu_f(d1/sq);
    t[512+tid] = gelu_f(d2/sq);
    t[768+tid] = gelu_f(d3/sq);
  }
  __syncthreads();
  if (tid < 160){
    int b = tid/40, o = tid%40;
    const float* tr = t + b*256; const float* wr = w2 + (size_t)o*256;
    float s=0;
    for (int j=0;j<256;j++) s = fmaf(tr[j], wr[j], s);
    out[tid] = s + b2[o];
  }
}

// =====================================================================
extern "C" void kernel_launch(void* const* d_in, const int* in_sizes, int n_in,
                              void* d_out, int out_size, void* d_ws, size_t ws_size,
                              hipStream_t stream)
{
  const float* x    = (const float*)d_in[0];
  const float* xyz  = (const float*)d_in[1];
  const float* mlpw = (const float*)d_in[2];
  const float* mlpb = (const float*)d_in[3];
  const float* c0l1 = (const float*)d_in[4];
  const float* c0l2 = (const float*)d_in[5];
  const float* L1[4] = {(const float*)d_in[6], (const float*)d_in[8],
                        (const float*)d_in[11], (const float*)d_in[14]};
  const float* L2[4] = {(const float*)d_in[7], (const float*)d_in[9],
                        (const float*)d_in[12], (const float*)d_in[15]};
  const float* SC[4] = {nullptr, (const float*)d_in[10],
                        (const float*)d_in[13], (const float*)d_in[16]};
  const float* hw1 = (const float*)d_in[17];
  const float* hw2 = (const float*)d_in[18];
  const float* hb2 = (const float*)d_in[19];
  float* out = (float*)d_out;

  float* ws = (float*)d_ws;
  const size_t MF = 1024*1024;
  float* D    = ws;               // 4M floats (pdist Gram)
  float* hA   = ws + 4*MF;
  float* hX   = ws + 5*MF;
  float* hP   = ws + 6*MF;
  float* hCT  = ws + 7*MF;
  float* hSH  = ws + 8*MF;
  float* hH1  = ws + 9*MF;
  float* hOUT = ws + 10*MF;
  int*   nbr0 = (int*)(ws + 11*MF);
  int*   nbrS = (int*)(ws + 11*MF + 400000);
  int*   nbrF = (int*)(ws + 11*MF + 450000);
  int*   sind = (int*)(ws + 11*MF + 500000);
  float* aa   = ws + 11*MF + 520000;
  float* cur1 = ws + 11*MF + 540000;
  float* cur2 = ws + 11*MF + 600000;
  float* part = ws + 11*MF + 680000;   // 2*NCHUNK*1024 floats
  float* stx  = ws + 11*MF + 760000;   // 1024 floats (mu/var)

  // ---- kNN on xyz, k=16, wave-per-query ----
  knn_wave<16><<<dim3(4096/4, 4),256,0,stream>>>(xyz, 4096, xyz, nullptr, 4096, nbr0, nullptr);

  // initial MLP + BN + gelu
  int tot0 = 4*4096*64;
  mlp_kernel<<<(tot0+255)/256,256,0,stream>>>(x, mlpw, mlpb, hA, 4096, tot0);
  stats_part_kernel<<<NCHUNK, 64, 0, stream>>>(hA, 16384, 64, part);
  bngelu_kernel<<<(tot0+255)/256,256,0,stream>>>(hA, part, 1.0f/16384.0f, 64, tot0);

  auto edgeconv = [&](const float* xin, const int* nbr, int K, int n, int Cin, int O1, int O2,
                      const float* l1, const float* l2, const float* sc,
                      float* outbuf)
  {
    int R = 4*n;
    dim3 gg1((O1+63)/64, (R+63)/64, 1);
    gemm_nt<true,false><<<gg1,256,0,stream>>>(xin, l1, hP, hCT, R, O1, Cin, Cin, 2*Cin, O1, Cin, 0,0,0, nullptr);
    int t1 = R*O1;
    gathermax_kernel<<<(t1+255)/256,256,0,stream>>>(hP, nbr, hCT, nullptr, hH1, n, n, O1, K, t1);
    stats_part_kernel<<<NCHUNK, O1, 0, stream>>>(hH1, R, O1, part);
    stats_fin<<<1, O1, 0, stream>>>(part, stx, 1.0f/R);

    // gemm2 applies BN+gelu on A-load (hH1 stays raw; single consumer)
    dim3 gg2((O2+63)/64, (R+63)/64, 1);
    gemm_nt<true,true><<<gg2,256,0,stream>>>(hH1, l2, hP, hCT, R, O2, O1, O1, 2*O1, O2, O1, 0,0,0, stx);
    const float* addB;
    if (sc) {
      gemm_nt<false,false><<<gg2,256,0,stream>>>(xin, sc, hSH, nullptr, R, O2, Cin, Cin, Cin, O2, 0, 0,0,0, nullptr);
      addB = hSH;
    } else addB = xin;
    int t2 = R*O2;
    gathermax_kernel<<<(t2+255)/256,256,0,stream>>>(hP, nbr, hCT, addB, outbuf, n, n, O2, K, t2);
    stats_part_kernel<<<NCHUNK, O2, 0, stream>>>(outbuf, R, O2, part);
    bngelu_kernel<<<(t2+255)/256,256,0,stream>>>(outbuf, part, 1.0f/R, O2, t2);
  };

  // first edge conv (uses xyz-kNN), x = hA
  edgeconv(hA, nbr0, 16, 4096, 64, 64, 64, c0l1, c0l2, nullptr, hOUT);
  float* hcur = hOUT;

  const float* cur = xyz; int nprev = 4096;
  int NPTSa[4] = {1024,256,64,16};
  int CinA[4] = {64,64,128,256}, O1A[4]={64,128,256,512}, O2A[4]={64,128,256,512};
  float* curbuf[2] = {cur1, cur2};

  for (int s=0;s<4;s++){
    int m = NPTSa[s];
    // ---- FPS ----
    if (nprev==4096)      fps_mw<8,512,1024><<<4,512,0,stream>>>(cur, nprev, sind);
    else if (nprev==1024) fps_sw<16,256><<<4,64,0,stream>>>(cur, nprev, sind);
    else if (nprev==256)  fps_sw<4,64><<<4,64,0,stream>>>(cur, nprev, sind);
    else                  fps_sw<1,16><<<4,64,0,stream>>>(cur, nprev, sind);
    // ---- kNN of sampled points vs prev points, k=8 (+ fused xyz mean) ----
    knn_wave<8><<<dim3(m/4,4),256,0,stream>>>(cur, nprev, cur, sind, m, nbrS, curbuf[s&1]);
    // feature downsample (max of 8 nbrs)
    int th = 4*m*CinA[s];
    gathermax_kernel<<<(th+255)/256,256,0,stream>>>(hcur, nbrS, nullptr, nullptr, hX, m, nprev, CinA[s], 8, th);
    // feature-space kNN: norms + Gram + wave top-8
    norms_kernel<<<(4*m+255)/256,256,0,stream>>>(hX, aa, CinA[s], 4*m);
    dim3 gp((m+63)/64, (m+63)/64, 4);
    gemm_nt<false,false><<<gp,256,0,stream>>>(hX, hX, D, nullptr, m, m, CinA[s],
                                        CinA[s], CinA[s], m, 0,
                                        (long)m*CinA[s], (long)m*CinA[s], (long)m*m, nullptr);
    topk_wave<8><<<dim3(m/4,4),256,0,stream>>>(D, aa, m, nbrF);
    // edge conv
    float* outbuf = (s&1) ? hOUT : hA;
    edgeconv(hX, nbrF, 8, m, CinA[s], O1A[s], O2A[s], L1[s], L2[s], SC[s], outbuf);
    hcur = outbuf;
    cur = curbuf[s&1]; nprev = m;
  }

  head_kernel<<<1,1024,0,stream>>>(hcur, hw1, hw2, hb2, out);
}

// Round 8
// 1826.472 us; speedup vs baseline: 1.2457x; 1.2457x over previous
//
#include <hip/hip_runtime.h>
#include <math.h>

#define NCHUNK 32
typedef unsigned long long ull;

__device__ __forceinline__ float gelu_f(float v){
  return 0.5f*v*(1.0f+erff(v*0.70710678118654752440f));
}

__device__ __forceinline__ unsigned flipf(float d){
  unsigned u = __float_as_uint(d);
  return (u & 0x80000000u) ? ~u : (u | 0x80000000u);
}

// ---- DPP helpers ----
template<int CTRL>
__device__ __forceinline__ ull dpp64(ull k){
  int lo = __builtin_amdgcn_update_dpp(0, (int)(unsigned)k,       CTRL, 0xF, 0xF, true);
  int hi = __builtin_amdgcn_update_dpp(0, (int)(unsigned)(k>>32), CTRL, 0xF, 0xF, true);
  return ((ull)(unsigned)hi<<32) | (unsigned)lo;
}
__device__ __forceinline__ ull rl64(ull k, int l){
  unsigned lo = (unsigned)__builtin_amdgcn_readlane((int)(unsigned)k, l);
  unsigned hi = (unsigned)__builtin_amdgcn_readlane((int)(unsigned)(k>>32), l);
  return ((ull)hi<<32) | lo;
}
// FPS keys are positive finite doubles bitwise (hi = float bits of nd>=0):
// u64 order == f64 order -> single v_max_f64 per combine.
__device__ __forceinline__ ull fmax64(ull a, ull b){
  return (ull)__double_as_longlong(fmax(__longlong_as_double((long long)a),
                                        __longlong_as_double((long long)b)));
}
__device__ __forceinline__ ull wave_fmax(ull k){
  k = fmax64(k, dpp64<0xB1>(k));
  k = fmax64(k, dpp64<0x4E>(k));
  k = fmax64(k, dpp64<0x141>(k));
  k = fmax64(k, dpp64<0x140>(k));
  ull a=rl64(k,0), b=rl64(k,16), c=rl64(k,32), d=rl64(k,48);
  return fmax64(fmax64(a,b), fmax64(c,d));
}
// u64-min (knn keys can have sign-bit hi words -> keep integer compares)
template<int CTRL>
__device__ __forceinline__ ull kmin_dpp(ull k){
  ull o = dpp64<CTRL>(k);
  return o < k ? o : k;
}
__device__ __forceinline__ ull wave_kmin(ull k){
  k = kmin_dpp<0xB1>(k);
  k = kmin_dpp<0x4E>(k);
  k = kmin_dpp<0x141>(k);
  k = kmin_dpp<0x140>(k);
  ull a=rl64(k,0), b=rl64(k,16), c=rl64(k,32), d=rl64(k,48);
  ull ab = a < b ? a : b, cd = c < d ? c : d;
  return ab < cd ? ab : cd;
}

// ================= device bodies =================

// ---- wave-per-query kNN; key=(flip(d)<<32)|idx; (d asc, idx asc) ----
template<int K, int T>
__device__ __forceinline__ void knn_body(
    const float* __restrict__ cand, int n,
    const float* __restrict__ qsrc, const int* __restrict__ qidx, int m,
    int* __restrict__ nbr, float* __restrict__ outc,
    int b, int qblk, char* smem)
{
  float* cx = (float*)smem; float* cy = cx+1024; float* cz = cy+1024; float* cbb = cz+1024;
  constexpr int NWV = T/64;
  int wv = threadIdx.x >> 6, lane = threadIdx.x & 63;
  int q = qblk*NWV + wv;
  const float* cb = cand + (size_t)b*3*n;
  int qi = qidx ? qidx[(size_t)b*m + q] : q;
  const float* qb = qsrc + (size_t)b*3*n;
  float qx = qb[qi], qy = qb[n+qi], qz = qb[2*n+qi];
  float aa = (qx*qx + qy*qy) + qz*qz;

  ull a[K];
  #pragma unroll
  for (int k=0;k<K;k++) a[k] = ~0ull;
  ull worst = ~0ull; int wslot = 0;

  for (int base=0; base<n; base+=1024){
    int cnt = min(1024, n-base);
    for (int j=threadIdx.x; j<cnt; j+=T){
      float x=cb[base+j], y=cb[n+base+j], z=cb[2*n+base+j];
      cx[j]=x; cy[j]=y; cz[j]=z; cbb[j]=(x*x+y*y)+z*z;
    }
    __syncthreads();
    int steps = cnt >> 6;
    for (int i=0;i<steps;i++){
      int j = lane + (i<<6);
      float d = aa + cbb[j] - 2.0f*((qx*cx[j]+qy*cy[j])+qz*cz[j]);
      ull key = ((ull)flipf(d)<<32) | (unsigned)(base+j);
      if (key < worst){
        #pragma unroll
        for (int k=0;k<K;k++) if (k==wslot) a[k] = key;
        worst = a[0]; wslot = 0;
        #pragma unroll
        for (int k=1;k<K;k++){
          bool g = a[k] > worst;
          worst = g ? a[k] : worst;
          wslot = g ? k : wslot;
        }
      }
    }
    __syncthreads();
  }

  // per-lane bitonic sort ascending
  #pragma unroll
  for (int kk=2; kk<=K; kk<<=1)
    #pragma unroll
    for (int jj=kk>>1; jj>0; jj>>=1)
      #pragma unroll
      for (int i=0;i<K;i++){
        int l = i ^ jj;
        if (l > i){
          bool dirUp = ((i & kk) == 0);
          ull x = a[i], y = a[l];
          bool sw = dirUp ? (x > y) : (x < y);
          a[i] = sw ? y : x;
          a[l] = sw ? x : y;
        }
      }

  ull head = a[0];
  int res[K];
  #pragma unroll
  for (int r=0; r<K; r++){
    ull mk = wave_kmin(head);
    res[r] = (int)(unsigned)mk;
    if (head == mk){
      #pragma unroll
      for (int i2=0;i2<K-1;i2++) a[i2]=a[i2+1];
      a[K-1] = ~0ull;
      head = a[0];
    }
  }
  if (lane == 0){
    int* o = nbr + ((size_t)b*m + q)*K;
    #pragma unroll
    for (int r=0;r<K;r++) o[r] = res[r];
  }
  if (outc != nullptr && lane < 3){
    const float* cd = cb + (size_t)lane*n;
    float s=0;
    #pragma unroll
    for (int k=0;k<K;k++) s += cd[res[k]];
    outc[((size_t)b*3 + lane)*m + q] = s * (1.0f/K);
  }
}

// ---- multi-wave FPS (stage 0) ----
template<int NP, int T, int M>
__device__ __forceinline__ void fps_mw_body(const float* __restrict__ cur, int n,
                                            int* __restrict__ sind, int b, char* smem)
{
  constexpr int NW = T/64;
  int tid = threadIdx.x;
  int wv = tid>>6;
  const float* cb = cur + (size_t)b*3*n;
  float4* lp = (float4*)smem;
  ull* wred = (ull*)(smem + sizeof(float4)*NP*T);  // [2][NW]
  float px[NP], py[NP], pz[NP], dmin[NP];
  unsigned nj[NP];
  #pragma unroll
  for (int s=0;s<NP;s++){
    int j = tid + s*T;
    px[s]=cb[j]; py[s]=cb[n+j]; pz[s]=cb[2*n+j]; dmin[s]=1e30f;
    nj[s] = (unsigned)(~j);
    lp[j] = make_float4(px[s],py[s],pz[s],0.f);
  }
  __syncthreads();
  float X = lp[0].x, Y = lp[0].y, Z = lp[0].z;
  if (tid==0) sind[(size_t)b*M] = 0;
  int p = 0;
  for (int step=1; step<M; step++){
    ull key[NP];
    #pragma unroll
    for (int s=0;s<NP;s++){
      float dx=px[s]-X, dy=py[s]-Y, dz=pz[s]-Z;
      float d = (dx*dx + dy*dy) + dz*dz;
      float nd = fminf(dmin[s], d);
      dmin[s] = nd;
      key[s] = ((ull)__float_as_uint(nd)<<32) | nj[s];
    }
    #pragma unroll
    for (int w=NP; w>1; w>>=1)
      #pragma unroll
      for (int i=0;i<NP;i++) if (i < (w>>1))
        key[i] = fmax64(key[i], key[i+(w>>1)]);
    ull wk = wave_fmax(key[0]);
    if ((tid&63)==0) wred[p*NW + wv] = wk;
    __syncthreads();
    ull gk = wred[p*NW];
    #pragma unroll
    for (int w=1;w<NW;w++) gk = fmax64(gk, wred[p*NW + w]);
    int gi = (int)(~(unsigned)gk);
    if (tid==0) sind[(size_t)b*M + step] = gi;
    float4 wp = lp[gi];
    X=wp.x; Y=wp.y; Z=wp.z;
    p ^= 1;
  }
}

// ---- single-wave FPS (stages 1-3): no barriers ----
template<int NP, int M>
__device__ __forceinline__ void fps_sw_body(const float* __restrict__ cur, int n,
                                            int* __restrict__ sind, int b, char* smem)
{
  int lane = threadIdx.x;   // 0..63
  const float* cb = cur + (size_t)b*3*n;
  float4* lp = (float4*)smem;
  float px[NP], py[NP], pz[NP], dmin[NP];
  unsigned nj[NP];
  #pragma unroll
  for (int s=0;s<NP;s++){
    int j = lane + s*64;
    px[s]=cb[j]; py[s]=cb[n+j]; pz[s]=cb[2*n+j]; dmin[s]=1e30f;
    nj[s] = (unsigned)(~j);
    lp[j] = make_float4(px[s],py[s],pz[s],0.f);
  }
  float X = lp[0].x, Y = lp[0].y, Z = lp[0].z;
  if (lane==0) sind[(size_t)b*M] = 0;
  for (int step=1; step<M; step++){
    ull key[NP];
    #pragma unroll
    for (int s=0;s<NP;s++){
      float dx=px[s]-X, dy=py[s]-Y, dz=pz[s]-Z;
      float d = (dx*dx + dy*dy) + dz*dz;
      float nd = fminf(dmin[s], d);
      dmin[s] = nd;
      key[s] = ((ull)__float_as_uint(nd)<<32) | nj[s];
    }
    #pragma unroll
    for (int w=NP; w>1; w>>=1)
      #pragma unroll
      for (int i=0;i<NP;i++) if (i < (w>>1))
        key[i] = fmax64(key[i], key[i+(w>>1)]);
    ull gk = wave_fmax(key[0]);
    int gi = (int)(~(unsigned)gk);
    if (lane==0) sind[(size_t)b*M + step] = gi;
    float4 wp = lp[gi];
    X=wp.x; Y=wp.y; Z=wp.z;
  }
}

// ---- tiled NT GEMM body (optional fused BN+gelu on A-load) ----
template<bool DUAL, bool BN>
__device__ __forceinline__ void gemm_body(
    const float* __restrict__ A, const float* __restrict__ B,
    float* __restrict__ out0, float* __restrict__ out1,
    int M, int N, int Kd, int lda, int ldb, int ldo, int boff,
    long sA, long sB, long sO, const float* __restrict__ bnst,
    int bxi, int byi, int bzi, char* smem)
{
  A += (size_t)bzi * sA; B += (size_t)bzi * sB;
  float* o0 = out0 + (size_t)bzi * sO;
  float* o1 = DUAL ? (out1 + (size_t)bzi * sO) : nullptr;
  int rowBase = byi*64, colBase = bxi*64;
  float (*As)[64]  = (float(*)[64])smem;
  float (*Bs0)[64] = (float(*)[64])(smem + 4096);
  float (*Bs1)[64] = (float(*)[64])(smem + 8192);
  int tid = threadIdx.x;
  int ty = tid>>4, tx = tid&15;
  float acc0[4][4] = {}, acc1[4][4] = {};
  int lr = tid>>2, lk = (tid&3)*4;
  for (int k0=0; k0<Kd; k0+=16) {
    float4 va = make_float4(0,0,0,0);
    int r = rowBase + lr;
    if (r < M) va = *(const float4*)(A + (size_t)r*lda + k0 + lk);
    if (BN){
      int c = k0 + lk;
      va.x = gelu_f((va.x - bnst[c+0]) / sqrtf(bnst[512+c+0] + 1e-5f));
      va.y = gelu_f((va.y - bnst[c+1]) / sqrtf(bnst[512+c+1] + 1e-5f));
      va.z = gelu_f((va.z - bnst[c+2]) / sqrtf(bnst[512+c+2] + 1e-5f));
      va.w = gelu_f((va.w - bnst[c+3]) / sqrtf(bnst[512+c+3] + 1e-5f));
    }
    As[lk+0][lr]=va.x; As[lk+1][lr]=va.y; As[lk+2][lr]=va.z; As[lk+3][lr]=va.w;
    float4 vb = make_float4(0,0,0,0), vb2 = make_float4(0,0,0,0);
    int c2 = colBase + lr;
    if (c2 < N) {
      vb = *(const float4*)(B + (size_t)c2*ldb + k0 + lk);
      if (DUAL) vb2 = *(const float4*)(B + (size_t)c2*ldb + boff + k0 + lk);
    }
    Bs0[lk+0][lr]=vb.x; Bs0[lk+1][lr]=vb.y; Bs0[lk+2][lr]=vb.z; Bs0[lk+3][lr]=vb.w;
    if (DUAL) {
      Bs1[lk+0][lr]=vb2.x-vb.x; Bs1[lk+1][lr]=vb2.y-vb.y;
      Bs1[lk+2][lr]=vb2.z-vb.z; Bs1[lk+3][lr]=vb2.w-vb.w;
    }
    __syncthreads();
    #pragma unroll
    for (int kk=0;kk<16;kk++){
      float4 a  = *(const float4*)&As[kk][ty*4];
      float4 b0 = *(const float4*)&Bs0[kk][tx*4];
      float av[4]={a.x,a.y,a.z,a.w};
      float b0v[4]={b0.x,b0.y,b0.z,b0.w};
      #pragma unroll
      for (int i=0;i<4;i++)
        #pragma unroll
        for (int j=0;j<4;j++) acc0[i][j] = fmaf(av[i], b0v[j], acc0[i][j]);
      if (DUAL) {
        float4 b1 = *(const float4*)&Bs1[kk][tx*4];
        float b1v[4]={b1.x,b1.y,b1.z,b1.w};
        #pragma unroll
        for (int i=0;i<4;i++)
          #pragma unroll
          for (int j=0;j<4;j++) acc1[i][j] = fmaf(av[i], b1v[j], acc1[i][j]);
      }
    }
    __syncthreads();
  }
  #pragma unroll
  for (int i=0;i<4;i++){
    int r = rowBase + ty*4 + i;
    if (r < M) {
      #pragma unroll
      for (int j=0;j<4;j++){
        int c = colBase + tx*4 + j;
        if (c < N) {
          o0[(size_t)r*ldo + c] = acc0[i][j];
          if (DUAL) o1[(size_t)r*ldo + c] = acc1[i][j];
        }
      }
    }
  }
}

// ---- gather + max body ----
__device__ __forceinline__ void gather_body(
    const float* __restrict__ P, const int* __restrict__ nbr,
    const float* __restrict__ addA, const float* __restrict__ addB,
    float* __restrict__ out, int n_out, int n_src, int O, int K, int total, int blk)
{
  int e = blk*256 + threadIdx.x;
  if (e >= total) return;
  int o = e % O; int r = e / O;
  int b = r / n_out; int i = r % n_out;
  const int* nb = nbr + ((size_t)b*n_out + i)*K;
  float mx = -1e38f;
  for (int k=0;k<K;k++){
    int j = nb[k];
    float v = P[((size_t)b*n_src + j)*O + o];
    mx = fmaxf(mx, v);
  }
  float res = mx;
  if (addA) res += addA[e];
  if (addB) res = addB[e] + res;
  out[e] = res;
}

// ================= global kernels =================

// mega1: [fps0 (blocks 0-3) | knn16 (4..2051) | mlp (2052..4099)] @512thr
__global__ __launch_bounds__(512) void mega1(
    const float* __restrict__ xyz, const float* __restrict__ x,
    const float* __restrict__ mlpw, const float* __restrict__ mlpb,
    int* __restrict__ sind0, int* __restrict__ nbr0, float* __restrict__ hA)
{
  __shared__ __align__(16) char SMEM[65664];
  int bid = blockIdx.x;
  if (bid < 4){
    fps_mw_body<8,512,1024>(xyz, 4096, sind0, bid, SMEM);
  } else if (bid < 4+2048){
    int kb = bid - 4;
    knn_body<16,512>(xyz, 4096, xyz, nullptr, 4096, nbr0, nullptr, kb>>9, kb&511, SMEM);
  } else {
    int e = (bid - 2052)*512 + threadIdx.x;
    if (e < 4*4096*64){
      int o = e & 63; int r = e >> 6;
      int b = r / 4096; int i = r % 4096;
      const float* xb = x + (size_t)b*3*4096;
      hA[e] = ((mlpw[o*3+0]*xb[i] + mlpw[o*3+1]*xb[4096+i]) + mlpw[o*3+2]*xb[2*4096+i]) + mlpb[o];
    }
  }
}

// standalone knn (2D grid), 256thr
__global__ __launch_bounds__(256) void knn_wave8(
    const float* cand, int n, const float* qsrc, const int* qidx, int m,
    int* nbr, float* outc)
{
  __shared__ __align__(16) char SMEM[16384];
  knn_body<8,256>(cand, n, qsrc, qidx, m, nbr, outc, blockIdx.y, blockIdx.x, SMEM);
}

// combo: [fps_sw (blocks 0-3, wave 0 only) | gemm (flattened)] @256thr
template<int NP, int M, bool DUAL, bool BN>
__global__ __launch_bounds__(256) void fps_gemm(
    const float* fcur, int fn, int* sind,
    const float* A, const float* B, float* out0, float* out1,
    int Mg, int Ng, int Kd, int lda, int ldb, int ldo, int boff,
    long sA, long sB, long sO, const float* bnst, int nbx, int nby)
{
  __shared__ __align__(16) char SMEM[(NP*64*16 > 12288) ? NP*64*16 : 12288];
  if (blockIdx.x < 4){
    if (threadIdx.x < 64) fps_sw_body<NP,M>(fcur, fn, sind, blockIdx.x, SMEM);
    return;
  }
  int l = blockIdx.x - 4;
  int bx = l % nbx, by = (l/nbx) % nby, bz = l/(nbx*nby);
  gemm_body<DUAL,BN>(A,B,out0,out1,Mg,Ng,Kd,lda,ldb,ldo,boff,sA,sB,sO,bnst,bx,by,bz,SMEM);
}

// combo: [knn8 (first KNB blocks) | gather] @256thr
__global__ __launch_bounds__(256) void knn_gather(
    const float* cand, int n, const float* qsrc, const int* qidx, int m,
    int* nbrOut, float* outc, int KNB,
    const float* P, const int* nbr, const float* addA, const float* addB,
    float* out, int n_out, int n_src, int O, int K, int total)
{
  __shared__ __align__(16) char SMEM[16384];
  if (blockIdx.x < KNB){
    int qpb = m/4;
    knn_body<8,256>(cand, n, qsrc, qidx, m, nbrOut, outc, blockIdx.x/qpb, blockIdx.x%qpb, SMEM);
    return;
  }
  gather_body(P, nbr, addA, addB, out, n_out, n_src, O, K, total, blockIdx.x - KNB);
}

// combo: [fps_sw | gather] @256thr
template<int NP, int M>
__global__ __launch_bounds__(256) void fps_gather(
    const float* fcur, int fn, int* sind,
    const float* P, const int* nbr, const float* addA, const float* addB,
    float* out, int n_out, int n_src, int O, int K, int total)
{
  __shared__ __align__(16) char SMEM[NP*64*16];
  if (blockIdx.x < 4){
    if (threadIdx.x < 64) fps_sw_body<NP,M>(fcur, fn, sind, blockIdx.x, SMEM);
    return;
  }
  gather_body(P, nbr, addA, addB, out, n_out, n_src, O, K, total, blockIdx.x - 4);
}

// combo: [knn8 | gemm] @256thr
__global__ __launch_bounds__(256) void knn_gemm(
    const float* cand, int n, const float* qsrc, const int* qidx, int m,
    int* nbrOut, float* outc, int KNB,
    const float* A, const float* B, float* out0,
    int Mg, int Ng, int Kd, int lda, int ldb, int ldo,
    long sA, long sB, long sO, int nbx, int nby)
{
  __shared__ __align__(16) char SMEM[16384];
  if (blockIdx.x < KNB){
    int qpb = m/4;
    knn_body<8,256>(cand, n, qsrc, qidx, m, nbrOut, outc, blockIdx.x/qpb, blockIdx.x%qpb, SMEM);
    return;
  }
  int l = blockIdx.x - KNB;
  int bx = l % nbx, by = (l/nbx) % nby, bz = l/(nbx*nby);
  gemm_body<false,false>(A,B,out0,nullptr,Mg,Ng,Kd,lda,ldb,ldo,0,sA,sB,sO,nullptr,bx,by,bz,SMEM);
}

// standalone wrappers
template<bool DUAL, bool BN>
__global__ __launch_bounds__(256) void gemm_nt(
    const float* A, const float* B, float* out0, float* out1,
    int M, int N, int Kd, int lda, int ldb, int ldo, int boff,
    long sA, long sB, long sO, const float* bnst)
{
  __shared__ __align__(16) char SMEM[12288];
  gemm_body<DUAL,BN>(A,B,out0,out1,M,N,Kd,lda,ldb,ldo,boff,sA,sB,sO,bnst,
                     blockIdx.x, blockIdx.y, blockIdx.z, SMEM);
}

__global__ __launch_bounds__(256) void gathermax_kernel(
    const float* P, const int* nbr, const float* addA, const float* addB,
    float* out, int n_out, int n_src, int O, int K, int total)
{
  gather_body(P, nbr, addA, addB, out, n_out, n_src, O, K, total, blockIdx.x);
}

// ---- top-K from Gram rows ----
template<int K>
__global__ __launch_bounds__(256) void topk_wave(
    const float* __restrict__ G, const float* __restrict__ aa, int m,
    int* __restrict__ nbr)
{
  __shared__ float abs_s[1024];
  int b = blockIdx.y;
  int wv = threadIdx.x >> 6, lane = threadIdx.x & 63;
  int q = blockIdx.x*4 + wv;
  const float* ab = aa + (size_t)b*m;
  for (int j=threadIdx.x; j<m; j+=256) abs_s[j] = ab[j];
  __syncthreads();
  float aq = ab[q];
  const float* Gq = G + ((size_t)b*m + q)*m;

  ull a[K];
  #pragma unroll
  for (int k=0;k<K;k++) a[k] = ~0ull;
  ull worst = ~0ull; int wslot = 0;

  int steps = (m+63)>>6;
  for (int i=0;i<steps;i++){
    int j = lane + (i<<6);
    ull key = ~0ull;
    if (j < m){
      float g = Gq[j];
      float d = aq + abs_s[j] - 2.0f*g;
      key = ((ull)flipf(d)<<32) | (unsigned)j;
    }
    if (key < worst){
      #pragma unroll
      for (int k=0;k<K;k++) if (k==wslot) a[k] = key;
      worst = a[0]; wslot = 0;
      #pragma unroll
      for (int k=1;k<K;k++){
        bool g = a[k] > worst;
        worst = g ? a[k] : worst;
        wslot = g ? k : wslot;
      }
    }
  }
  #pragma unroll
  for (int kk=2; kk<=K; kk<<=1)
    #pragma unroll
    for (int jj=kk>>1; jj>0; jj>>=1)
      #pragma unroll
      for (int i=0;i<K;i++){
        int l = i ^ jj;
        if (l > i){
          bool dirUp = ((i & kk) == 0);
          ull x = a[i], y = a[l];
          bool sw = dirUp ? (x > y) : (x < y);
          a[i] = sw ? y : x;
          a[l] = sw ? x : y;
        }
      }
  ull head = a[0];
  int res[K];
  #pragma unroll
  for (int r=0; r<K; r++){
    ull mk = wave_kmin(head);
    res[r] = (int)(unsigned)mk;
    if (head == mk){
      #pragma unroll
      for (int i2=0;i2<K-1;i2++) a[i2]=a[i2+1];
      a[K-1] = ~0ull;
      head = a[0];
    }
  }
  if (lane == 0){
    int* o = nbr + ((size_t)b*m + q)*K;
    #pragma unroll
    for (int r=0;r<K;r++) o[r] = res[r];
  }
}

// ---- stats / bn / norms / head ----
__global__ void stats_part_kernel(const float* __restrict__ x, int R, int O,
                                  float* __restrict__ part)
{
  int o = threadIdx.x;
  int chunk = blockIdx.x;
  int per = (R + NCHUNK - 1)/NCHUNK;
  int r0 = chunk*per, r1 = min(r0+per, R);
  float s=0, q=0;
  for (int r=r0; r<r1; r++){ float v = x[(size_t)r*O + o]; s+=v; q+=v*v; }
  part[(size_t)chunk*1024 + o] = s;
  part[(size_t)(NCHUNK+chunk)*1024 + o] = q;
}

__global__ void stats_fin(const float* __restrict__ part, float* __restrict__ st,
                          float invR)
{
  int o = threadIdx.x;
  float s=0, q=0;
  #pragma unroll 4
  for (int c=0;c<NCHUNK;c++){
    s += part[(size_t)c*1024 + o];
    q += part[(size_t)(NCHUNK+c)*1024 + o];
  }
  float mu = s*invR;
  st[o] = mu;
  st[512+o] = q*invR - mu*mu;
}

__global__ __launch_bounds__(256) void bngelu_kernel(float* __restrict__ x,
    const float* __restrict__ part, float invR, int O, int total)
{
  __shared__ float mu_s[512], var_s[512];
  for (int oo=threadIdx.x; oo<O; oo+=256){
    float s=0, q=0;
    #pragma unroll 4
    for (int c=0;c<NCHUNK;c++){
      s += part[(size_t)c*1024 + oo];
      q += part[(size_t)(NCHUNK+c)*1024 + oo];
    }
    float mu = s*invR;
    mu_s[oo] = mu;
    var_s[oo] = q*invR - mu*mu;
  }
  __syncthreads();
  int e = blockIdx.x*256 + threadIdx.x;
  if (e >= total) return;
  int o = e % O;
  float v = (x[e]-mu_s[o]) / sqrtf(var_s[o] + 1e-5f);
  x[e] = gelu_f(v);
}

__global__ __launch_bounds__(256) void norms_kernel(const float* __restrict__ h,
    float* __restrict__ aa, int C, int total)
{
  int e = blockIdx.x*256 + threadIdx.x;
  if (e >= total) return;
  const float* r = h + (size_t)e*C;
  float s=0;
  for (int c=0;c<C;c++) s += r[c]*r[c];
  aa[e]=s;
}

__global__ __launch_bounds__(1024) void head_kernel(const float* __restrict__ h,
    const float* __restrict__ w1, const float* __restrict__ w2,
    const float* __restrict__ b2, float* __restrict__ out)
{
  __shared__ __align__(16) float g[4*512];
  __shared__ __align__(16) float t[4*256];
  int tid = threadIdx.x;
  for (int e=tid; e<2048; e+=1024){
    int b=e>>9, c=e&511;
    float s=0;
    for (int p=0;p<16;p++) s += h[((size_t)(b*16+p))*512 + c];
    g[e] = s * (1.0f/16.0f);
  }
  __syncthreads();
  {
    int b = tid>>8, j = tid&255;
    const float4* gr = (const float4*)(g + b*512);
    const float4* wr = (const float4*)(w1 + (size_t)j*512);
    float s=0;
    for (int c=0;c<128;c++){
      float4 a=gr[c], w=wr[c];
      s = fmaf(a.x,w.x, fmaf(a.y,w.y, fmaf(a.z,w.z, fmaf(a.w,w.w, s))));
    }
    t[tid] = s;
  }
  __syncthreads();
  if (tid < 256){
    float v0=t[tid], v1=t[256+tid], v2=t[512+tid], v3=t[768+tid];
    float mu = ((v0+v1)+v2+v3)*0.25f;
    float d0=v0-mu, d1=v1-mu, d2=v2-mu, d3=v3-mu;
    float var = ((d0*d0+d1*d1)+d2*d2+d3*d3)*0.25f;
    float sq = sqrtf(var + 1e-5f);
    t[tid]     = gelu_f(d0/sq);
    t[256+tid] = gelu_f(d1/sq);
    t[512+tid] = gelu_f(d2/sq);
    t[768+tid] = gelu_f(d3/sq);
  }
  __syncthreads();
  if (tid < 160){
    int b = tid/40, o = tid%40;
    const float* tr = t + b*256; const float* wr = w2 + (size_t)o*256;
    float s=0;
    for (int j=0;j<256;j++) s = fmaf(tr[j], wr[j], s);
    out[tid] = s + b2[o];
  }
}

// =====================================================================
extern "C" void kernel_launch(void* const* d_in, const int* in_sizes, int n_in,
                              void* d_out, int out_size, void* d_ws, size_t ws_size,
                              hipStream_t stream)
{
  const float* x    = (const float*)d_in[0];
  const float* xyz  = (const float*)d_in[1];
  const float* mlpw = (const float*)d_in[2];
  const float* mlpb = (const float*)d_in[3];
  const float* c0l1 = (const float*)d_in[4];
  const float* c0l2 = (const float*)d_in[5];
  const float* L1[4] = {(const float*)d_in[6], (const float*)d_in[8],
                        (const float*)d_in[11], (const float*)d_in[14]};
  const float* L2[4] = {(const float*)d_in[7], (const float*)d_in[9],
                        (const float*)d_in[12], (const float*)d_in[15]};
  const float* SC[4] = {nullptr, (const float*)d_in[10],
                        (const float*)d_in[13], (const float*)d_in[16]};
  const float* hw1 = (const float*)d_in[17];
  const float* hw2 = (const float*)d_in[18];
  const float* hb2 = (const float*)d_in[19];
  float* out = (float*)d_out;

  float* ws = (float*)d_ws;
  const size_t MF = 1024*1024;
  float* D    = ws;               // 4M floats (Gram)
  float* hA   = ws + 4*MF;
  float* hX   = ws + 5*MF;
  float* hP   = ws + 6*MF;
  float* hCT  = ws + 7*MF;
  float* hSH  = ws + 8*MF;
  float* hH1  = ws + 9*MF;
  float* hOUT = ws + 10*MF;
  float* aux  = ws + 11*MF;
  int*   nbr0  = (int*)aux;                 aux += 262144;
  int*   nbrS0 = (int*)aux;                 aux += 32768;
  int*   nbrS1 = (int*)aux;                 aux += 8192;
  int*   nbrS2 = (int*)aux;                 aux += 2048;
  int*   nbrS3 = (int*)aux;                 aux += 512;
  int*   nbrF  = (int*)aux;                 aux += 32768;
  int*   sind0 = (int*)aux;                 aux += 4096;
  int*   sind1 = (int*)aux;                 aux += 1024;
  int*   sind2 = (int*)aux;                 aux += 256;
  int*   sind3 = (int*)aux;                 aux += 64;
  float* aa    = aux;                       aux += 4096;
  float* cur1  = aux;                       aux += 12288;
  float* cur2  = aux;                       aux += 3072;
  float* cur3  = aux;                       aux += 768;
  float* part  = aux;                       aux += 65536;
  float* stx   = aux;                       aux += 1024;

  int tot0 = 4*4096*64;

  // [fps0 | knn16 | mlp]
  mega1<<<4100, 512, 0, stream>>>(xyz, x, mlpw, mlpb, sind0, nbr0, hA);
  // knn8 stage0: sampled 1024 vs 4096, fused xyz-mean -> cur1
  knn_wave8<<<dim3(256,4),256,0,stream>>>(xyz, 4096, xyz, sind0, 1024, nbrS0, cur1);
  // BN of mlp out
  stats_part_kernel<<<NCHUNK, 64, 0, stream>>>(hA, 16384, 64, part);
  bngelu_kernel<<<(tot0+255)/256,256,0,stream>>>(hA, part, 1.0f/16384.0f, 64, tot0);

  // ---- edgeconv0 (n=4096, Cin=64, O1=O2=64, K=16, sc=None) with geometry pairings ----
  // gemm1 + fps1(cur1, n=1024 -> 256 picks)
  fps_gemm<16,256,true,false><<<4+256,256,0,stream>>>(cur1, 1024, sind1,
      hA, c0l1, hP, hCT, 16384, 64, 64, 64, 128, 64, 64, 0,0,0, nullptr, 1, 256);
  // gather1 + knn8_1 (m=256 vs 1024) -> nbrS1, cur2
  knn_gather<<<256+4096,256,0,stream>>>(cur1, 1024, cur1, sind1, 256, nbrS1, cur2, 256,
      hP, nbr0, hCT, nullptr, hH1, 4096, 4096, 64, 16, 1048576);
  stats_part_kernel<<<NCHUNK, 64, 0, stream>>>(hH1, 16384, 64, part);
  stats_fin<<<1, 64, 0, stream>>>(part, stx, 1.0f/16384.0f);
  // gemm2 (BN-fused A) + fps2(cur2, n=256 -> 64 picks)
  fps_gemm<4,64,true,true><<<4+256,256,0,stream>>>(cur2, 256, sind2,
      hH1, c0l2, hP, hCT, 16384, 64, 64, 64, 128, 64, 64, 0,0,0, stx, 1, 256);
  // gather2 (+xin add) + knn8_2 (m=64 vs 256) -> nbrS2, cur3
  knn_gather<<<64+4096,256,0,stream>>>(cur2, 256, cur2, sind2, 64, nbrS2, cur3, 64,
      hP, nbr0, hCT, hA, hOUT, 4096, 4096, 64, 16, 1048576);
  stats_part_kernel<<<NCHUNK, 64, 0, stream>>>(hOUT, 16384, 64, part);
  bngelu_kernel<<<(1048576+255)/256,256,0,stream>>>(hOUT, part, 1.0f/16384.0f, 64, 1048576);
  // h0 = hOUT

  // ---- stage0 pre (m=1024, Cin=64) ----
  // feature downsample + fps3(cur3, n=64 -> 16 picks)
  fps_gather<1,16><<<4+1024,256,0,stream>>>(cur3, 64, sind3,
      hOUT, nbrS0, nullptr, nullptr, hX, 1024, 4096, 64, 8, 262144);
  norms_kernel<<<16,256,0,stream>>>(hX, aa, 64, 4096);
  // Gram + knn8_3 (m=16 vs 64, no mean)
  knn_gemm<<<16+1024,256,0,stream>>>(cur3, 64, cur3, sind3, 16, nbrS3, nullptr, 16,
      hX, hX, D, 1024, 1024, 64, 64, 64, 1024,
      (long)1024*64, (long)1024*64, (long)1024*1024, 16, 16);
  topk_wave<8><<<dim3(256,4),256,0,stream>>>(D, aa, 1024, nbrF);

  auto edgeconv = [&](const float* xin, const int* nbr, int K, int n, int Cin, int O1, int O2,
                      const float* l1, const float* l2, const float* sc, float* outbuf)
  {
    int R = 4*n;
    dim3 gg1((O1+63)/64, (R+63)/64, 1);
    gemm_nt<true,false><<<gg1,256,0,stream>>>(xin, l1, hP, hCT, R, O1, Cin, Cin, 2*Cin, O1, Cin, 0,0,0, nullptr);
    int t1 = R*O1;
    gathermax_kernel<<<(t1+255)/256,256,0,stream>>>(hP, nbr, hCT, nullptr, hH1, n, n, O1, K, t1);
    stats_part_kernel<<<NCHUNK, O1, 0, stream>>>(hH1, R, O1, part);
    stats_fin<<<1, O1, 0, stream>>>(part, stx, 1.0f/R);
    dim3 gg2((O2+63)/64, (R+63)/64, 1);
    gemm_nt<true,true><<<gg2,256,0,stream>>>(hH1, l2, hP, hCT, R, O2, O1, O1, 2*O1, O2, O1, 0,0,0, stx);
    const float* addB;
    if (sc) {
      gemm_nt<false,false><<<gg2,256,0,stream>>>(xin, sc, hSH, nullptr, R, O2, Cin, Cin, Cin, O2, 0, 0,0,0, nullptr);
      addB = hSH;
    } else addB = xin;
    int t2 = R*O2;
    gathermax_kernel<<<(t2+255)/256,256,0,stream>>>(hP, nbr, hCT, addB, outbuf, n, n, O2, K, t2);
    stats_part_kernel<<<NCHUNK, O2, 0, stream>>>(outbuf, R, O2, part);
    bngelu_kernel<<<(t2+255)/256,256,0,stream>>>(outbuf, part, 1.0f/R, O2, t2);
  };

  // stage0 conv: hX -> hA
  edgeconv(hX, nbrF, 8, 1024, 64, 64, 64, L1[0], L2[0], SC[0], hA);

  // ---- stages 1-3 (geometry precomputed) ----
  const int   mArr[3]   = {256, 64, 16};
  const int   nsrcArr[3]= {1024, 256, 64};
  const int   CinArr[3] = {64, 128, 256};
  const int   O1Arr[3]  = {128, 256, 512};
  const int*  nbrSs[3]  = {nbrS1, nbrS2, nbrS3};
  float* hcur = hA;
  for (int s=0;s<3;s++){
    int m = mArr[s], nsrc = nsrcArr[s], Cin = CinArr[s], O1 = O1Arr[s], O2 = O1Arr[s];
    int th = 4*m*Cin;
    gathermax_kernel<<<(th+255)/256,256,0,stream>>>(hcur, nbrSs[s], nullptr, nullptr, hX, m, nsrc, Cin, 8, th);
    norms_kernel<<<(4*m+255)/256,256,0,stream>>>(hX, aa, Cin, 4*m);
    dim3 gp((m+63)/64, (m+63)/64, 4);
    gemm_nt<false,false><<<gp,256,0,stream>>>(hX, hX, D, nullptr, m, m, Cin, Cin, Cin, m, 0,
                                              (long)m*Cin, (long)m*Cin, (long)m*m, nullptr);
    topk_wave<8><<<dim3(m/4,4),256,0,stream>>>(D, aa, m, nbrF);
    float* outbuf = (s&1) ? hA : hOUT;   // s1->hOUT, s2->hA, s3->hOUT
    edgeconv(hX, nbrF, 8, m, Cin, O1, O2, L1[s+1], L2[s+1], SC[s+1], outbuf);
    hcur = outbuf;
  }

  head_kernel<<<1,1024,0,stream>>>(hcur, hw1, hw2, hb2, out);
}